// Round 1
// baseline (120.664 us; speedup 1.0000x reference)
//
#include <hip/hip_runtime.h>

#define NN 512
#define DD 1024

// ---------------- GEMM: sim = F1 (512x1024) * F2^T (1024x512), all f32 ----------------
// 32x32 output tile per block, 256 threads, 2x2 micro-tile, K-chunks of 32 staged in LDS.
__global__ __launch_bounds__(256) void gemm_kernel(const float* __restrict__ A,
                                                   const float* __restrict__ B,
                                                   float* __restrict__ C) {
  __shared__ float As[32][33];  // +1 pad: conflict-free reads
  __shared__ float Bs[32][33];
  const int t = threadIdx.x;
  const int tx = t & 15, ty = t >> 4;
  const int row0 = blockIdx.y * 32, col0 = blockIdx.x * 32;
  const int lr = t >> 3;          // 0..31 (row within tile)
  const int lc = (t & 7) << 2;    // 0,4,...,28 (k-col within chunk)
  float acc00 = 0.f, acc01 = 0.f, acc10 = 0.f, acc11 = 0.f;
  for (int kb = 0; kb < DD; kb += 32) {
    const float4 av = *(const float4*)&A[(row0 + lr) * DD + kb + lc];
    const float4 bv = *(const float4*)&B[(col0 + lr) * DD + kb + lc];
    __syncthreads();
    As[lr][lc] = av.x; As[lr][lc + 1] = av.y; As[lr][lc + 2] = av.z; As[lr][lc + 3] = av.w;
    Bs[lr][lc] = bv.x; Bs[lr][lc + 1] = bv.y; Bs[lr][lc + 2] = bv.z; Bs[lr][lc + 3] = bv.w;
    __syncthreads();
#pragma unroll
    for (int k = 0; k < 32; ++k) {
      const float a0 = As[ty * 2][k], a1 = As[ty * 2 + 1][k];
      const float b0 = Bs[tx * 2][k], b1 = Bs[tx * 2 + 1][k];
      acc00 = fmaf(a0, b0, acc00);
      acc01 = fmaf(a0, b1, acc01);
      acc10 = fmaf(a1, b0, acc10);
      acc11 = fmaf(a1, b1, acc11);
    }
  }
  float* Cp = &C[(row0 + ty * 2) * NN + col0 + tx * 2];
  Cp[0] = acc00; Cp[1] = acc01;
  Cp[NN] = acc10; Cp[NN + 1] = acc11;
}

// ---------------- Loss: one block per (direction, row) ----------------
// Row i (dir 0) / col j (dir 1) of sim staged to LDS; loop positives p (block-uniform
// skip of mask[p]==0), all lanes cover the 512 n-slots; negatives masked by multiply.
__global__ __launch_bounds__(256) void loss_kernel(const float* __restrict__ sim,
                                                   const int* __restrict__ mask,
                                                   const unsigned char* __restrict__ ms1,
                                                   const unsigned char* __restrict__ ms2,
                                                   float* __restrict__ loss_blk,
                                                   float* __restrict__ pair_blk) {
  __shared__ float s[NN];
  __shared__ float mf[NN];
  __shared__ float red[256];
  const int b = blockIdx.x;          // 0..1023
  const int dir = b >> 9;
  const int idx = b & (NN - 1);
  const int t = threadIdx.x;
  const unsigned char msel = (dir == 0) ? ms1[idx] : ms2[idx];
  if (!msel) {
    if (t == 0) { loss_blk[b] = 0.f; pair_blk[b] = 0.f; }
    return;
  }
  float cnt = 0.f;
  if (dir == 0) {
    for (int c = t; c < NN; c += 256) {
      s[c] = sim[idx * NN + c];
      const float m = (float)mask[idx * NN + c];
      mf[c] = m; cnt += m;
    }
  } else {
    for (int r = t; r < NN; r += 256) {
      s[r] = sim[r * NN + idx];
      const float m = (float)mask[r * NN + idx];
      mf[r] = m; cnt += m;
    }
  }
  __syncthreads();
  float acc = 0.f;
  for (int p = 0; p < NN; ++p) {
    const float mp = mf[p];
    if (mp != 0.f) {                 // block-uniform branch: whole wave skips
      const float sp = s[p];
#pragma unroll
      for (int h = 0; h < 2; ++h) {
        const int n = (h << 8) + t;
        const float x = s[n] - sp;
        // stable softplus: max(x,0) + log1p(exp(-|x|))
        const float spl = fmaxf(x, 0.f) + __logf(1.f + __expf(-fabsf(x)));
        acc += (1.f - mf[n]) * spl;
      }
    }
  }
  // deterministic block reduction of loss
  red[t] = acc; __syncthreads();
  for (int st = 128; st > 0; st >>= 1) {
    if (t < st) red[t] += red[t + st];
    __syncthreads();
  }
  if (t == 0) loss_blk[b] = red[0];
  __syncthreads();
  // deterministic block reduction of positive count -> pair count
  red[t] = cnt; __syncthreads();
  for (int st = 128; st > 0; st >>= 1) {
    if (t < st) red[t] += red[t + st];
    __syncthreads();
  }
  if (t == 0) {
    const float np_ = red[0];
    pair_blk[b] = np_ * ((float)NN - np_);   // exact: <= 65536 < 2^24
  }
}

// ---------------- Final: reduce 1024 block partials, divide ----------------
__global__ __launch_bounds__(256) void final_kernel(const float* __restrict__ loss_blk,
                                                    const float* __restrict__ pair_blk,
                                                    float* __restrict__ out) {
  __shared__ double rl[256];
  __shared__ double rp[256];
  const int t = threadIdx.x;
  double al = 0.0, ap = 0.0;
  for (int i = t; i < 1024; i += 256) { al += (double)loss_blk[i]; ap += (double)pair_blk[i]; }
  rl[t] = al; rp[t] = ap; __syncthreads();
  for (int st = 128; st > 0; st >>= 1) {
    if (t < st) { rl[t] += rl[t + st]; rp[t] += rp[t + st]; }
    __syncthreads();
  }
  if (t == 0) {
    const double pn = rp[0];
    out[0] = (float)((pn > 0.0) ? rl[0] / pn : rl[0]);
  }
}

extern "C" void kernel_launch(void* const* d_in, const int* in_sizes, int n_in,
                              void* d_out, int out_size, void* d_ws, size_t ws_size,
                              hipStream_t stream) {
  const float* f1 = (const float*)d_in[0];
  const float* f2 = (const float*)d_in[1];
  const int* mask = (const int*)d_in[2];
  const unsigned char* ms1 = (const unsigned char*)d_in[3];  // jnp.bool_ -> 1 byte
  const unsigned char* ms2 = (const unsigned char*)d_in[4];
  float* sim      = (float*)d_ws;               // 512*512 f32 = 1 MB
  float* loss_blk = sim + NN * NN;              // 1024 f32
  float* pair_blk = loss_blk + 1024;            // 1024 f32

  gemm_kernel<<<dim3(16, 16), 256, 0, stream>>>(f1, f2, sim);
  loss_kernel<<<1024, 256, 0, stream>>>(sim, mask, ms1, ms2, loss_blk, pair_blk);
  final_kernel<<<1, 256, 0, stream>>>(loss_blk, pair_blk, (float*)d_out);
}

// Round 2
// 67.703 us; speedup vs baseline: 1.7822x; 1.7822x over previous
//
#include <hip/hip_runtime.h>

#define NN 512
#define DD 1024

// ---------------- GEMM: sim = F1 (512x1024) * F2^T (1024x512), f32, split-K ----------------
// 32x32 tile, 256 threads, 2x2 micro-tile. LDS stored k-major (pad 34) so the
// inner loop reads float2 (ds_read_b64, broadcast across lanes) instead of 4x b32.
__global__ __launch_bounds__(256) void gemm_kernel(const float* __restrict__ A,
                                                   const float* __restrict__ B,
                                                   float* __restrict__ C,
                                                   int ksplit) {
  __shared__ float Ask[32][34];  // [k][row], stride 34 keeps float2 reads 8B-aligned
  __shared__ float Bsk[32][34];
  const int t = threadIdx.x;
  const int tx = t & 15, ty = t >> 4;
  const int row0 = blockIdx.y * 32, col0 = blockIdx.x * 32;
  const int kspan = DD / ksplit;
  const int kbeg = blockIdx.z * kspan;
  const int lr = t >> 3;          // 0..31
  const int lc = (t & 7) << 2;    // 0,4,...,28
  float acc00 = 0.f, acc01 = 0.f, acc10 = 0.f, acc11 = 0.f;
  for (int kb = 0; kb < kspan; kb += 32) {
    const float4 av = *(const float4*)&A[(row0 + lr) * DD + kbeg + kb + lc];
    const float4 bv = *(const float4*)&B[(col0 + lr) * DD + kbeg + kb + lc];
    __syncthreads();
    Ask[lc + 0][lr] = av.x; Ask[lc + 1][lr] = av.y; Ask[lc + 2][lr] = av.z; Ask[lc + 3][lr] = av.w;
    Bsk[lc + 0][lr] = bv.x; Bsk[lc + 1][lr] = bv.y; Bsk[lc + 2][lr] = bv.z; Bsk[lc + 3][lr] = bv.w;
    __syncthreads();
#pragma unroll
    for (int k = 0; k < 32; ++k) {
      const float2 a = *(const float2*)&Ask[k][ty * 2];
      const float2 b = *(const float2*)&Bsk[k][tx * 2];
      acc00 = fmaf(a.x, b.x, acc00);
      acc01 = fmaf(a.x, b.y, acc01);
      acc10 = fmaf(a.y, b.x, acc10);
      acc11 = fmaf(a.y, b.y, acc11);
    }
  }
  float* Cp = &C[(size_t)blockIdx.z * NN * NN + (row0 + ty * 2) * NN + col0 + tx * 2];
  Cp[0] = acc00; Cp[1] = acc01;
  Cp[NN] = acc10; Cp[NN + 1] = acc11;
}

__device__ __forceinline__ float softplus_term(float x) {
  // stable softplus: max(x,0) + log1p(exp(-|x|)); native exp/log (trans pipe)
  return fmaxf(x, 0.f) + __logf(1.f + __expf(-fabsf(x)));
}

// ---------------- Loss: one block per (direction, row) ----------------
// Deterministic prefix-scan compaction of positives/negatives, then p-loop over
// compacted positives in float4 chunks (1 broadcast ds_read_b128 per 4 p's),
// negatives held in registers. 4 independent accumulator chains for ILP.
__global__ __launch_bounds__(256) void loss_kernel(const float* __restrict__ sim,
                                                   const int* __restrict__ mask,
                                                   const unsigned char* __restrict__ ms1,
                                                   const unsigned char* __restrict__ ms2,
                                                   float* __restrict__ loss_blk,
                                                   float* __restrict__ pair_blk,
                                                   int ksplit) {
  __shared__ __align__(16) float pos_s[NN];
  __shared__ __align__(16) float neg_s[NN];
  __shared__ int sc[256];
  __shared__ float red[256];
  const int b = blockIdx.x;          // 0..1023
  const int dir = b >> 9;
  const int idx = b & (NN - 1);
  const int t = threadIdx.x;
  const unsigned char msel = dir ? ms2[idx] : ms1[idx];
  if (!msel) {
    if (t == 0) { loss_blk[b] = 0.f; pair_blk[b] = 0.f; }
    return;
  }
  // Each thread owns elements c0 = t and c1 = t + 256 of the row/column.
  float v0, v1; int m0, m1;
  if (dir == 0) {
    v0 = sim[idx * NN + t];
    v1 = sim[idx * NN + t + 256];
    if (ksplit == 2) {
      v0 += sim[NN * NN + idx * NN + t];
      v1 += sim[NN * NN + idx * NN + t + 256];
    }
    m0 = mask[idx * NN + t];
    m1 = mask[idx * NN + t + 256];
  } else {
    v0 = sim[t * NN + idx];
    v1 = sim[(t + 256) * NN + idx];
    if (ksplit == 2) {
      v0 += sim[NN * NN + t * NN + idx];
      v1 += sim[NN * NN + (t + 256) * NN + idx];
    }
    m0 = mask[t * NN + idx];
    m1 = mask[(t + 256) * NN + idx];
  }
  const int pcnt = m0 + m1;
  // Hillis-Steele inclusive scan over 256 per-thread positive counts.
  sc[t] = pcnt;
  __syncthreads();
  for (int off = 1; off < 256; off <<= 1) {
    const int add = (t >= off) ? sc[t - off] : 0;
    __syncthreads();
    sc[t] += add;
    __syncthreads();
  }
  const int posb = sc[t] - pcnt;       // exclusive positives before my elements
  const int npos = sc[255];
  const int negb = 2 * t - posb;       // exclusive negatives before my elements
  {
    int pb = posb, nb = negb;
    if (m0) pos_s[pb++] = v0; else neg_s[nb++] = v0;
    if (m1) pos_s[pb] = v1;   else neg_s[nb] = v1;
  }
  __syncthreads();
  const int nneg = 2 * 256 - npos;     // 512 - npos
  const int npos4 = npos & ~3;

  float acc = 0.f;
  for (int base = 0; base < nneg; base += 256) {
    const int n = base + t;
    if (n < nneg) {
      const float sn = neg_s[n];
      float a0 = 0.f, a1 = 0.f, a2 = 0.f, a3 = 0.f;
      for (int pb = 0; pb < npos4; pb += 4) {
        const float4 sp = *(const float4*)&pos_s[pb];  // broadcast b128
        a0 += softplus_term(sn - sp.x);
        a1 += softplus_term(sn - sp.y);
        a2 += softplus_term(sn - sp.z);
        a3 += softplus_term(sn - sp.w);
      }
      for (int p = npos4; p < npos; ++p) a0 += softplus_term(sn - pos_s[p]);
      acc += (a0 + a1) + (a2 + a3);
    }
  }

  // deterministic block tree-reduction of loss
  red[t] = acc; __syncthreads();
  for (int st = 128; st > 0; st >>= 1) {
    if (t < st) red[t] += red[t + st];
    __syncthreads();
  }
  if (t == 0) {
    loss_blk[b] = red[0];
    pair_blk[b] = (float)npos * (float)(512 - npos);  // exact in f32 (<= 65536)
  }
}

// ---------------- Final: reduce 1024 block partials, divide ----------------
__global__ __launch_bounds__(256) void final_kernel(const float* __restrict__ loss_blk,
                                                    const float* __restrict__ pair_blk,
                                                    float* __restrict__ out) {
  __shared__ double rl[256];
  __shared__ double rp[256];
  const int t = threadIdx.x;
  double al = 0.0, ap = 0.0;
  for (int i = t; i < 1024; i += 256) { al += (double)loss_blk[i]; ap += (double)pair_blk[i]; }
  rl[t] = al; rp[t] = ap; __syncthreads();
  for (int st = 128; st > 0; st >>= 1) {
    if (t < st) { rl[t] += rl[t + st]; rp[t] += rp[t + st]; }
    __syncthreads();
  }
  if (t == 0) {
    const double pn = rp[0];
    out[0] = (float)((pn > 0.0) ? rl[0] / pn : rl[0]);
  }
}

extern "C" void kernel_launch(void* const* d_in, const int* in_sizes, int n_in,
                              void* d_out, int out_size, void* d_ws, size_t ws_size,
                              hipStream_t stream) {
  const float* f1 = (const float*)d_in[0];
  const float* f2 = (const float*)d_in[1];
  const int* mask = (const int*)d_in[2];
  const unsigned char* ms1 = (const unsigned char*)d_in[3];  // jnp.bool_ -> 1 byte
  const unsigned char* ms2 = (const unsigned char*)d_in[4];

  // Workspace layout: ksplit partial sim buffers, then block partials.
  const size_t need2 = (size_t)2 * NN * NN * sizeof(float) + 2048 * sizeof(float);
  const int ksplit = (ws_size >= need2) ? 2 : 1;

  float* sim      = (float*)d_ws;                     // ksplit * 1 MB
  float* loss_blk = sim + (size_t)ksplit * NN * NN;   // 1024 f32
  float* pair_blk = loss_blk + 1024;                  // 1024 f32

  gemm_kernel<<<dim3(16, 16, ksplit), 256, 0, stream>>>(f1, f2, sim, ksplit);
  loss_kernel<<<1024, 256, 0, stream>>>(sim, mask, ms1, ms2, loss_blk, pair_blk, ksplit);
  final_kernel<<<1, 256, 0, stream>>>(loss_blk, pair_blk, (float*)d_out);
}

// Round 3
// 55.730 us; speedup vs baseline: 2.1651x; 1.2148x over previous
//
#include <hip/hip_runtime.h>

#define NN 512
#define DD 1024

// ---------------- GEMM: sim partial = F1 * F2^T over a K-span ----------------
// 32x32 tile, 256 threads, 2x2 micro-tile, k-major LDS (float2 broadcast reads).
__global__ __launch_bounds__(256) void gemm_kernel(const float* __restrict__ A,
                                                   const float* __restrict__ B,
                                                   float* __restrict__ C,
                                                   int ksplit) {
  __shared__ float Ask[32][34];
  __shared__ float Bsk[32][34];
  const int t = threadIdx.x;
  const int tx = t & 15, ty = t >> 4;
  const int row0 = blockIdx.y * 32, col0 = blockIdx.x * 32;
  const int kspan = DD / ksplit;
  const int kbeg = blockIdx.z * kspan;
  const int lr = t >> 3;
  const int lc = (t & 7) << 2;
  float acc00 = 0.f, acc01 = 0.f, acc10 = 0.f, acc11 = 0.f;
  for (int kb = 0; kb < kspan; kb += 32) {
    const float4 av = *(const float4*)&A[(row0 + lr) * DD + kbeg + kb + lc];
    const float4 bv = *(const float4*)&B[(col0 + lr) * DD + kbeg + kb + lc];
    __syncthreads();
    Ask[lc + 0][lr] = av.x; Ask[lc + 1][lr] = av.y; Ask[lc + 2][lr] = av.z; Ask[lc + 3][lr] = av.w;
    Bsk[lc + 0][lr] = bv.x; Bsk[lc + 1][lr] = bv.y; Bsk[lc + 2][lr] = bv.z; Bsk[lc + 3][lr] = bv.w;
    __syncthreads();
#pragma unroll
    for (int k = 0; k < 32; ++k) {
      const float2 a = *(const float2*)&Ask[k][ty * 2];
      const float2 b = *(const float2*)&Bsk[k][tx * 2];
      acc00 = fmaf(a.x, b.x, acc00);
      acc01 = fmaf(a.x, b.y, acc01);
      acc10 = fmaf(a.y, b.x, acc10);
      acc11 = fmaf(a.y, b.y, acc11);
    }
  }
  float* Cp = &C[(size_t)blockIdx.z * NN * NN + (row0 + ty * 2) * NN + col0 + tx * 2];
  Cp[0] = acc00; Cp[1] = acc01;
  Cp[NN] = acc10; Cp[NN + 1] = acc11;
}

// ---------------- Phase A: compact each (dir,row) into pos (parity-split) / neg lists ----------------
__global__ __launch_bounds__(256) void prep_kernel(const float* __restrict__ sim,
                                                   const int* __restrict__ mask,
                                                   const unsigned char* __restrict__ ms1,
                                                   const unsigned char* __restrict__ ms2,
                                                   float* __restrict__ posA,
                                                   float* __restrict__ negA,
                                                   int* __restrict__ nposA,
                                                   float* __restrict__ pairA,
                                                   int ks) {
  __shared__ int sc[256];
  const int b = blockIdx.x;          // 0..1023 (dir<<9 | idx)
  const int dir = b >> 9;
  const int idx = b & (NN - 1);
  const int t = threadIdx.x;
  const unsigned char sel = dir ? ms2[idx] : ms1[idx];
  if (!sel) {
    if (t == 0) { nposA[b] = -1; pairA[b] = 0.f; }
    return;
  }
  float v0 = 0.f, v1 = 0.f; int m0, m1;
  if (dir == 0) {
    const int b0 = idx * NN + t, b1 = b0 + 256;
    for (int z = 0; z < ks; ++z) { v0 += sim[z * NN * NN + b0]; v1 += sim[z * NN * NN + b1]; }
    m0 = mask[b0]; m1 = mask[b1];
  } else {
    const int b0 = t * NN + idx, b1 = (t + 256) * NN + idx;
    for (int z = 0; z < ks; ++z) { v0 += sim[z * NN * NN + b0]; v1 += sim[z * NN * NN + b1]; }
    m0 = mask[b0]; m1 = mask[b1];
  }
  const int pcnt = m0 + m1;
  sc[t] = pcnt;
  __syncthreads();
  for (int off = 1; off < 256; off <<= 1) {
    const int add = (t >= off) ? sc[t - off] : 0;
    __syncthreads();
    sc[t] += add;
    __syncthreads();
  }
  const int posb = sc[t] - pcnt;     // exclusive positive prefix
  const int npos = sc[255];
  int pb = posb, nb = 2 * t - posb;
  float* pr = posA + (size_t)b * NN;
  float* ng = negA + (size_t)b * NN;
  // positives parity-split by compact index: sublist ph holds pb = ph, ph+2, ...
  if (m0) { pr[(pb & 1) * 256 + (pb >> 1)] = v0; ++pb; } else { ng[nb++] = v0; }
  if (m1) { pr[(pb & 1) * 256 + (pb >> 1)] = v1; }       else { ng[nb] = v1; }
  if (t == 0) {
    nposA[b] = npos;
    pairA[b] = (float)npos * (float)(NN - npos);   // exact (<= 65536)
  }
}

// ---------------- Phase B: pair loss. 4 blocks per (dir,row): (neg-half q&1) x (pos-parity q>>1) ----------------
__global__ __launch_bounds__(256) void pairs_kernel(const float* __restrict__ posA,
                                                    const float* __restrict__ negA,
                                                    const int* __restrict__ nposA,
                                                    float* __restrict__ lossB) {
  __shared__ float red[256];
  const int bid = blockIdx.x;        // 0..4095
  const int rd = bid >> 2;
  const int q = bid & 3;
  const int t = threadIdx.x;
  const int npos = nposA[rd];
  float sum = 0.f;
  if (npos >= 0) {
    const int nneg = NN - npos;
    const int ph = q >> 1;
    const int i = ((q & 1) << 8) + t;
    if (i < nneg) {
      const float sn = negA[(size_t)rd * NN + i];
      const int cnt = (npos - ph + 1) >> 1;            // parity-sublist length
      const float* pp = posA + (size_t)rd * NN + ph * 256;
      // softplus(x) = max(x,0) + log1p(e^{-|x|});  sum the log1p's as one log of a product:
      // each factor in (1,2], <=67 factors/chain -> prod <= 2^67, safe in f32.
      float l0 = 0.f, l1 = 0.f, l2 = 0.f, l3 = 0.f;
      float p0 = 1.f, p1 = 1.f, p2 = 1.f, p3 = 1.f;
      const int cnt4 = cnt & ~3;
#pragma unroll 2
      for (int k = 0; k < cnt4; k += 4) {
        const float4 sp = *(const float4*)&pp[k];      // broadcast b128 via L1
        const float x0 = sn - sp.x, x1 = sn - sp.y, x2 = sn - sp.z, x3 = sn - sp.w;
        l0 += fmaxf(x0, 0.f); p0 = fmaf(p0, __expf(-fabsf(x0)), p0);
        l1 += fmaxf(x1, 0.f); p1 = fmaf(p1, __expf(-fabsf(x1)), p1);
        l2 += fmaxf(x2, 0.f); p2 = fmaf(p2, __expf(-fabsf(x2)), p2);
        l3 += fmaxf(x3, 0.f); p3 = fmaf(p3, __expf(-fabsf(x3)), p3);
      }
      for (int k = cnt4; k < cnt; ++k) {
        const float x = sn - pp[k];
        l0 += fmaxf(x, 0.f); p0 = fmaf(p0, __expf(-fabsf(x)), p0);
      }
      sum = ((l0 + l1) + (l2 + l3)) +
            ((__logf(p0) + __logf(p1)) + (__logf(p2) + __logf(p3)));
    }
  }
  red[t] = sum; __syncthreads();
  for (int st = 128; st > 0; st >>= 1) {
    if (t < st) red[t] += red[t + st];
    __syncthreads();
  }
  if (t == 0) lossB[bid] = red[0];
}

// ---------------- Final: reduce partials, divide ----------------
__global__ __launch_bounds__(256) void final2_kernel(const float* __restrict__ lossB,
                                                     const float* __restrict__ pairA,
                                                     float* __restrict__ out) {
  __shared__ double rl[256];
  __shared__ double rp[256];
  const int t = threadIdx.x;
  double al = 0.0, ap = 0.0;
  for (int i = t; i < 4096; i += 256) al += (double)lossB[i];
  for (int i = t; i < 1024; i += 256) ap += (double)pairA[i];
  rl[t] = al; rp[t] = ap; __syncthreads();
  for (int st = 128; st > 0; st >>= 1) {
    if (t < st) { rl[t] += rl[t + st]; rp[t] += rp[t + st]; }
    __syncthreads();
  }
  if (t == 0) {
    const double pn = rp[0];
    out[0] = (float)((pn > 0.0) ? rl[0] / pn : rl[0]);
  }
}

// ---------------- Fallback monolithic loss (small ws) ----------------
__global__ __launch_bounds__(256) void loss_mono_kernel(const float* __restrict__ sim,
                                                        const int* __restrict__ mask,
                                                        const unsigned char* __restrict__ ms1,
                                                        const unsigned char* __restrict__ ms2,
                                                        float* __restrict__ loss_blk,
                                                        float* __restrict__ pair_blk,
                                                        int ksplit) {
  __shared__ __align__(16) float pos_s[NN];
  __shared__ __align__(16) float neg_s[NN];
  __shared__ int sc[256];
  __shared__ float red[256];
  const int b = blockIdx.x;
  const int dir = b >> 9;
  const int idx = b & (NN - 1);
  const int t = threadIdx.x;
  const unsigned char msel = dir ? ms2[idx] : ms1[idx];
  if (!msel) {
    if (t == 0) { loss_blk[b] = 0.f; pair_blk[b] = 0.f; }
    return;
  }
  float v0, v1; int m0, m1;
  if (dir == 0) {
    v0 = sim[idx * NN + t]; v1 = sim[idx * NN + t + 256];
    if (ksplit == 2) { v0 += sim[NN * NN + idx * NN + t]; v1 += sim[NN * NN + idx * NN + t + 256]; }
    m0 = mask[idx * NN + t]; m1 = mask[idx * NN + t + 256];
  } else {
    v0 = sim[t * NN + idx]; v1 = sim[(t + 256) * NN + idx];
    if (ksplit == 2) { v0 += sim[NN * NN + t * NN + idx]; v1 += sim[NN * NN + (t + 256) * NN + idx]; }
    m0 = mask[t * NN + idx]; m1 = mask[(t + 256) * NN + idx];
  }
  const int pcnt = m0 + m1;
  sc[t] = pcnt; __syncthreads();
  for (int off = 1; off < 256; off <<= 1) {
    const int add = (t >= off) ? sc[t - off] : 0;
    __syncthreads(); sc[t] += add; __syncthreads();
  }
  const int posb = sc[t] - pcnt;
  const int npos = sc[255];
  int pb = posb, nb = 2 * t - posb;
  if (m0) pos_s[pb++] = v0; else neg_s[nb++] = v0;
  if (m1) pos_s[pb] = v1;   else neg_s[nb] = v1;
  __syncthreads();
  const int nneg = NN - npos;
  const int npos4 = npos & ~3;
  float acc = 0.f;
  for (int base = 0; base < nneg; base += 256) {
    const int n = base + t;
    if (n < nneg) {
      const float sn = neg_s[n];
      float l0 = 0.f, p0 = 1.f, l1 = 0.f, p1 = 1.f, l2 = 0.f, p2 = 1.f, l3 = 0.f, p3 = 1.f;
      for (int pk = 0; pk < npos4; pk += 4) {
        const float4 sp = *(const float4*)&pos_s[pk];
        const float x0 = sn - sp.x, x1 = sn - sp.y, x2 = sn - sp.z, x3 = sn - sp.w;
        l0 += fmaxf(x0, 0.f); p0 = fmaf(p0, __expf(-fabsf(x0)), p0);
        l1 += fmaxf(x1, 0.f); p1 = fmaf(p1, __expf(-fabsf(x1)), p1);
        l2 += fmaxf(x2, 0.f); p2 = fmaf(p2, __expf(-fabsf(x2)), p2);
        l3 += fmaxf(x3, 0.f); p3 = fmaf(p3, __expf(-fabsf(x3)), p3);
      }
      for (int p = npos4; p < npos; ++p) {
        const float x = sn - pos_s[p];
        l0 += fmaxf(x, 0.f); p0 = fmaf(p0, __expf(-fabsf(x)), p0);
      }
      acc += ((l0 + l1) + (l2 + l3)) +
             ((__logf(p0) + __logf(p1)) + (__logf(p2) + __logf(p3)));
    }
  }
  red[t] = acc; __syncthreads();
  for (int st = 128; st > 0; st >>= 1) {
    if (t < st) red[t] += red[t + st];
    __syncthreads();
  }
  if (t == 0) {
    loss_blk[b] = red[0];
    pair_blk[b] = (float)npos * (float)(NN - npos);
  }
}

__global__ __launch_bounds__(256) void final_mono_kernel(const float* __restrict__ loss_blk,
                                                         const float* __restrict__ pair_blk,
                                                         float* __restrict__ out) {
  __shared__ double rl[256];
  __shared__ double rp[256];
  const int t = threadIdx.x;
  double al = 0.0, ap = 0.0;
  for (int i = t; i < 1024; i += 256) { al += (double)loss_blk[i]; ap += (double)pair_blk[i]; }
  rl[t] = al; rp[t] = ap; __syncthreads();
  for (int st = 128; st > 0; st >>= 1) {
    if (t < st) { rl[t] += rl[t + st]; rp[t] += rp[t + st]; }
    __syncthreads();
  }
  if (t == 0) {
    const double pn = rp[0];
    out[0] = (float)((pn > 0.0) ? rl[0] / pn : rl[0]);
  }
}

extern "C" void kernel_launch(void* const* d_in, const int* in_sizes, int n_in,
                              void* d_out, int out_size, void* d_ws, size_t ws_size,
                              hipStream_t stream) {
  const float* f1 = (const float*)d_in[0];
  const float* f2 = (const float*)d_in[1];
  const int* mask = (const int*)d_in[2];
  const unsigned char* ms1 = (const unsigned char*)d_in[3];
  const unsigned char* ms2 = (const unsigned char*)d_in[4];
  float* out = (float*)d_out;

  // full two-phase path requirement in floats: ks*NN*NN (sim partials) + 2*1024*NN (pos+neg)
  // + 1024 (npos int) + 1024 (pairA) + 4096 (lossB)
  auto need = [](int ks) -> size_t {
    return ((size_t)ks * NN * NN + 2u * 1024u * NN + 1024u + 1024u + 4096u) * sizeof(float);
  };
  int ks = 0;
  if (ws_size >= need(4)) ks = 4;
  else if (ws_size >= need(2)) ks = 2;
  else if (ws_size >= need(1)) ks = 1;

  if (ks > 0) {
    float* sim   = (float*)d_ws;
    float* posA  = sim + (size_t)ks * NN * NN;
    float* negA  = posA + (size_t)1024 * NN;
    int*   nposA = (int*)(negA + (size_t)1024 * NN);
    float* pairA = (float*)(nposA + 1024);
    float* lossB = pairA + 1024;
    gemm_kernel<<<dim3(16, 16, ks), 256, 0, stream>>>(f1, f2, sim, ks);
    prep_kernel<<<1024, 256, 0, stream>>>(sim, mask, ms1, ms2, posA, negA, nposA, pairA, ks);
    pairs_kernel<<<4096, 256, 0, stream>>>(posA, negA, nposA, lossB);
    final2_kernel<<<1, 256, 0, stream>>>(lossB, pairA, out);
  } else {
    const size_t need2 = (size_t)2 * NN * NN * sizeof(float) + 2048 * sizeof(float);
    const int ksplit = (ws_size >= need2) ? 2 : 1;
    float* sim      = (float*)d_ws;
    float* loss_blk = sim + (size_t)ksplit * NN * NN;
    float* pair_blk = loss_blk + 1024;
    gemm_kernel<<<dim3(16, 16, ksplit), 256, 0, stream>>>(f1, f2, sim, ksplit);
    loss_mono_kernel<<<1024, 256, 0, stream>>>(sim, mask, ms1, ms2, loss_blk, pair_blk, ksplit);
    final_mono_kernel<<<1, 256, 0, stream>>>(loss_blk, pair_blk, out);
  }
}

// Round 4
// 40.156 us; speedup vs baseline: 3.0049x; 1.3878x over previous
//
#include <hip/hip_runtime.h>

#define NN 512
#define DD 1024

typedef __attribute__((ext_vector_type(8))) short short8;
typedef __attribute__((ext_vector_type(4))) float f32x4;

__device__ __forceinline__ float fast_exp2(float x) {
#if __has_builtin(__builtin_amdgcn_exp2f)
  return __builtin_amdgcn_exp2f(x);
#else
  return __expf(x * 0.6931471805599453f);
#endif
}
__device__ __forceinline__ float fast_log2(float x) {
#if __has_builtin(__builtin_amdgcn_logf)
  return __builtin_amdgcn_logf(x);
#else
  return __logf(x) * 1.4426950408889634f;
#endif
}

// split f32 -> bf16 hi/lo (truncation; lo absorbs hi's error, net rel err ~2^-16)
__device__ __forceinline__ void cvt2(float f0, float f1, unsigned& hi, unsigned& lo) {
  const unsigned u0 = __float_as_uint(f0), u1 = __float_as_uint(f1);
  const unsigned h0 = u0 & 0xFFFF0000u, h1 = u1 & 0xFFFF0000u;
  const float r0 = f0 - __uint_as_float(h0);
  const float r1 = f1 - __uint_as_float(h1);
  hi = (u0 >> 16) | h1;
  lo = (__float_as_uint(r0) >> 16) | (__float_as_uint(r1) & 0xFFFF0000u);
}

__device__ __forceinline__ void store8(unsigned short* hp, unsigned short* lp,
                                       float4 f0, float4 f1) {
  uint4 hi, lo;
  cvt2(f0.x, f0.y, hi.x, lo.x);
  cvt2(f0.z, f0.w, hi.y, lo.y);
  cvt2(f1.x, f1.y, hi.z, lo.z);
  cvt2(f1.z, f1.w, hi.w, lo.w);
  *(uint4*)hp = hi;
  *(uint4*)lp = lo;
}

// ---------------- GEMM: sim partial = F1 * F2^T over a K-span, bf16-split MFMA ----------------
// 64x64 tile, 256 threads = 4 waves (2x2), each wave 32x32 via 2x2 16x16x32 frags.
// 3 MFMA products (hh, hl, lh) recover near-f32 precision. Writes sim AND simT partials.
__global__ __launch_bounds__(256) void gemm_kernel(const float* __restrict__ A,
                                                   const float* __restrict__ B,
                                                   float* __restrict__ simP,
                                                   float* __restrict__ simTP,
                                                   int ks) {
  __shared__ unsigned short Ah[64][40];  // row stride 80B (5x16B): 16B-aligned, ~2-way banks
  __shared__ unsigned short Al[64][40];
  __shared__ unsigned short Bh[64][40];
  __shared__ unsigned short Bl[64][40];
  const int t = threadIdx.x;
  const int lane = t & 63;
  const int w = t >> 6;
  const int wm = w >> 1, wn = w & 1;
  const int row0 = blockIdx.y * 64, col0 = blockIdx.x * 64;
  const int z = blockIdx.z;
  const int kspan = DD / ks;
  const int kbeg = z * kspan;
  const int srow = t >> 2;        // 0..63
  const int skq = (t & 3) << 3;   // 0,8,16,24

  f32x4 acc[2][2] = {{{0.f, 0.f, 0.f, 0.f}, {0.f, 0.f, 0.f, 0.f}},
                     {{0.f, 0.f, 0.f, 0.f}, {0.f, 0.f, 0.f, 0.f}}};

  const int ksel = (lane >> 4) << 3;   // 0,8,16,24 (k-offset of my frag slice)
  const int ar0 = wm * 32 + (lane & 15);
  const int br0 = wn * 32 + (lane & 15);

  for (int kb = 0; kb < kspan; kb += 32) {
    const float4 a0 = *(const float4*)&A[(row0 + srow) * DD + kbeg + kb + skq];
    const float4 a1 = *(const float4*)&A[(row0 + srow) * DD + kbeg + kb + skq + 4];
    const float4 b0 = *(const float4*)&B[(col0 + srow) * DD + kbeg + kb + skq];
    const float4 b1 = *(const float4*)&B[(col0 + srow) * DD + kbeg + kb + skq + 4];
    __syncthreads();
    store8(&Ah[srow][skq], &Al[srow][skq], a0, a1);
    store8(&Bh[srow][skq], &Bl[srow][skq], b0, b1);
    __syncthreads();
    short8 ah0 = *(const short8*)&Ah[ar0][ksel];
    short8 ah1 = *(const short8*)&Ah[ar0 + 16][ksel];
    short8 al0 = *(const short8*)&Al[ar0][ksel];
    short8 al1 = *(const short8*)&Al[ar0 + 16][ksel];
    short8 bh0 = *(const short8*)&Bh[br0][ksel];
    short8 bh1 = *(const short8*)&Bh[br0 + 16][ksel];
    short8 bl0 = *(const short8*)&Bl[br0][ksel];
    short8 bl1 = *(const short8*)&Bl[br0 + 16][ksel];
    acc[0][0] = __builtin_amdgcn_mfma_f32_16x16x32_bf16(ah0, bh0, acc[0][0], 0, 0, 0);
    acc[0][1] = __builtin_amdgcn_mfma_f32_16x16x32_bf16(ah0, bh1, acc[0][1], 0, 0, 0);
    acc[1][0] = __builtin_amdgcn_mfma_f32_16x16x32_bf16(ah1, bh0, acc[1][0], 0, 0, 0);
    acc[1][1] = __builtin_amdgcn_mfma_f32_16x16x32_bf16(ah1, bh1, acc[1][1], 0, 0, 0);
    acc[0][0] = __builtin_amdgcn_mfma_f32_16x16x32_bf16(ah0, bl0, acc[0][0], 0, 0, 0);
    acc[0][1] = __builtin_amdgcn_mfma_f32_16x16x32_bf16(ah0, bl1, acc[0][1], 0, 0, 0);
    acc[1][0] = __builtin_amdgcn_mfma_f32_16x16x32_bf16(ah1, bl0, acc[1][0], 0, 0, 0);
    acc[1][1] = __builtin_amdgcn_mfma_f32_16x16x32_bf16(ah1, bl1, acc[1][1], 0, 0, 0);
    acc[0][0] = __builtin_amdgcn_mfma_f32_16x16x32_bf16(al0, bh0, acc[0][0], 0, 0, 0);
    acc[0][1] = __builtin_amdgcn_mfma_f32_16x16x32_bf16(al0, bh1, acc[0][1], 0, 0, 0);
    acc[1][0] = __builtin_amdgcn_mfma_f32_16x16x32_bf16(al1, bh0, acc[1][0], 0, 0, 0);
    acc[1][1] = __builtin_amdgcn_mfma_f32_16x16x32_bf16(al1, bh1, acc[1][1], 0, 0, 0);
  }

  float* Cz = simP + (size_t)z * NN * NN;
  float* Tz = simTP + (size_t)z * NN * NN;
#pragma unroll
  for (int qm = 0; qm < 2; ++qm) {
    const int mb = row0 + wm * 32 + qm * 16 + ((lane >> 4) << 2);
#pragma unroll
    for (int qn = 0; qn < 2; ++qn) {
      const int n = col0 + wn * 32 + qn * 16 + (lane & 15);
#pragma unroll
      for (int r = 0; r < 4; ++r) Cz[(mb + r) * NN + n] = acc[qm][qn][r];
      *(f32x4*)&Tz[n * NN + mb] = acc[qm][qn];  // D-frag is m-contiguous: free transpose
    }
  }
}

// ---------------- Phase A: ballot-scan compaction into pos/neg lists (pre-scaled by log2e) ----------------
__global__ __launch_bounds__(256) void prep_kernel(const float* __restrict__ simP,
                                                   const float* __restrict__ simTP,
                                                   const int* __restrict__ mask,
                                                   const unsigned char* __restrict__ ms1,
                                                   const unsigned char* __restrict__ ms2,
                                                   float* __restrict__ posA,
                                                   float* __restrict__ negA,
                                                   int* __restrict__ nposA,
                                                   float* __restrict__ pairA,
                                                   int ks) {
  __shared__ int wsum[4];
  const int b = blockIdx.x;         // 0..1023 (dir<<9 | idx)
  const int dir = b >> 9;
  const int idx = b & (NN - 1);
  const int t = threadIdx.x;
  const int lane = t & 63;
  const int w = t >> 6;
  const unsigned char sel = dir ? ms2[idx] : ms1[idx];
  if (!sel) {
    if (t == 0) { nposA[b] = -1; pairA[b] = 0.f; }
    return;
  }
  float v0 = 0.f, v1 = 0.f;
  int m0, m1;
  if (dir == 0) {
    for (int z = 0; z < ks; ++z) {
      v0 += simP[(size_t)z * NN * NN + idx * NN + t];
      v1 += simP[(size_t)z * NN * NN + idx * NN + t + 256];
    }
    m0 = mask[idx * NN + t];
    m1 = mask[idx * NN + t + 256];
  } else {
    for (int z = 0; z < ks; ++z) {
      v0 += simTP[(size_t)z * NN * NN + idx * NN + t];
      v1 += simTP[(size_t)z * NN * NN + idx * NN + t + 256];
    }
    m0 = mask[t * NN + idx];
    m1 = mask[(t + 256) * NN + idx];
  }
  const unsigned long long b0 = __ballot(m0 != 0);
  const unsigned long long b1 = __ballot(m1 != 0);
  const unsigned long long lt = (1ull << lane) - 1ull;
  const int c0 = __popcll(b0 & lt), c1 = __popcll(b1 & lt);
  const int t0 = __popcll(b0), t1 = __popcll(b1);
  if (lane == 0) wsum[w] = t0 + t1;
  __syncthreads();
  int wp = 0, npos = 0;
#pragma unroll
  for (int q = 0; q < 4; ++q) {
    const int s = wsum[q];
    npos += s;
    if (q < w) wp += s;
  }
  const float LOG2E = 1.4426950408889634f;
  float* pr = posA + (size_t)b * NN;
  float* ng = negA + (size_t)b * NN;
  // element order: wave-major, c0-block then c1-block within wave
  const int e0 = (w << 7) + lane;
  const int e1 = e0 + 64;
  const int pos0 = wp + c0;
  const int pos1 = wp + t0 + c1;
  if (m0) pr[pos0] = v0 * LOG2E; else ng[e0 - pos0] = v0 * LOG2E;
  if (m1) pr[pos1] = v1 * LOG2E; else ng[e1 - pos1] = v1 * LOG2E;
  if (t == 0) {
    nposA[b] = npos;
    pairA[b] = (float)npos * (float)(NN - npos);  // exact (<= 65536)
  }
}

// ---------------- Phase B: pair loss. 2 blocks per (dir,row), positives in LDS ----------------
__global__ __launch_bounds__(256) void pairs_kernel(const float* __restrict__ posA,
                                                    const float* __restrict__ negA,
                                                    const int* __restrict__ nposA,
                                                    float* __restrict__ lossB) {
  __shared__ __align__(16) float posL[NN];
  __shared__ float wred[4];
  const int bid = blockIdx.x;       // 0..2047
  const int rd = bid >> 1;
  const int t = threadIdx.x;
  const int lane = t & 63;
  const int w = t >> 6;
  const int npos = nposA[rd];
  if (npos < 0) {
    if (t == 0) lossB[bid] = 0.f;
    return;
  }
  for (int j = t; j < npos; j += 256) posL[j] = posA[(size_t)rd * NN + j];
  __syncthreads();
  const int nneg = NN - npos;
  const int i = ((bid & 1) << 8) + t;
  float sum = 0.f;
  if (i < nneg) {
    const float sn = negA[(size_t)rd * NN + i];   // already scaled by log2e
    float l0 = 0.f, l1 = 0.f, l2 = 0.f, l3 = 0.f, lg = 0.f;
    const int npos4 = npos & ~3;
    int p = 0;
    while (p < npos4) {                            // segments of <=256: chains <=2^64, no overflow
      const int pend = min(npos4, p + 256);
      float p0 = 1.f, p1 = 1.f, p2 = 1.f, p3 = 1.f;
      for (; p < pend; p += 4) {
        const float4 sp = *(const float4*)&posL[p];  // broadcast ds_read_b128
        const float x0 = sn - sp.x; l0 += fmaxf(x0, 0.f); p0 = fmaf(p0, fast_exp2(-fabsf(x0)), p0);
        const float x1 = sn - sp.y; l1 += fmaxf(x1, 0.f); p1 = fmaf(p1, fast_exp2(-fabsf(x1)), p1);
        const float x2 = sn - sp.z; l2 += fmaxf(x2, 0.f); p2 = fmaf(p2, fast_exp2(-fabsf(x2)), p2);
        const float x3 = sn - sp.w; l3 += fmaxf(x3, 0.f); p3 = fmaf(p3, fast_exp2(-fabsf(x3)), p3);
      }
      lg += (fast_log2(p0) + fast_log2(p1)) + (fast_log2(p2) + fast_log2(p3));
    }
    {
      float p0 = 1.f;
      for (int k = npos4; k < npos; ++k) {
        const float x = sn - posL[k];
        l0 += fmaxf(x, 0.f);
        p0 = fmaf(p0, fast_exp2(-fabsf(x)), p0);
      }
      lg += fast_log2(p0);
    }
    sum = (((l0 + l1) + (l2 + l3)) + lg) * 0.6931471805599453f;  // back to natural units
  }
  for (int off = 32; off > 0; off >>= 1) sum += __shfl_down(sum, off);
  if (lane == 0) wred[w] = sum;
  __syncthreads();
  if (t == 0) lossB[bid] = (wred[0] + wred[1]) + (wred[2] + wred[3]);
}

// ---------------- Final: reduce partials, divide ----------------
__global__ __launch_bounds__(256) void final_kernel(const float* __restrict__ lossB,
                                                    const float* __restrict__ pairA,
                                                    float* __restrict__ out) {
  __shared__ double rl[256];
  __shared__ double rp[256];
  const int t = threadIdx.x;
  double al = 0.0, ap = 0.0;
  for (int i = t; i < 2048; i += 256) al += (double)lossB[i];
  for (int i = t; i < 1024; i += 256) ap += (double)pairA[i];
  rl[t] = al; rp[t] = ap; __syncthreads();
  for (int st = 128; st > 0; st >>= 1) {
    if (t < st) { rl[t] += rl[t + st]; rp[t] += rp[t + st]; }
    __syncthreads();
  }
  if (t == 0) {
    const double pn = rp[0];
    out[0] = (float)((pn > 0.0) ? rl[0] / pn : rl[0]);
  }
}

extern "C" void kernel_launch(void* const* d_in, const int* in_sizes, int n_in,
                              void* d_out, int out_size, void* d_ws, size_t ws_size,
                              hipStream_t stream) {
  const float* f1 = (const float*)d_in[0];
  const float* f2 = (const float*)d_in[1];
  const int* mask = (const int*)d_in[2];
  const unsigned char* ms1 = (const unsigned char*)d_in[3];
  const unsigned char* ms2 = (const unsigned char*)d_in[4];
  float* out = (float*)d_out;

  auto need = [](int ks) -> size_t {
    return ((size_t)2 * ks * NN * NN + 2u * 1024u * NN + 1024u + 1024u + 2048u) * sizeof(float);
  };
  const int ks = (ws_size >= need(4)) ? 4 : 1;   // ws observed ~268 MB; need(4) ~12.6 MB

  float* sim   = (float*)d_ws;                      // ks * 1 MB
  float* simT  = sim + (size_t)ks * NN * NN;        // ks * 1 MB
  float* posA  = simT + (size_t)ks * NN * NN;       // 2 MB
  float* negA  = posA + (size_t)1024 * NN;          // 2 MB
  int*   nposA = (int*)(negA + (size_t)1024 * NN);  // 4 KB
  float* pairA = (float*)(nposA + 1024);            // 4 KB
  float* lossB = pairA + 1024;                      // 8 KB

  gemm_kernel<<<dim3(8, 8, ks), 256, 0, stream>>>(f1, f2, sim, simT, ks);
  prep_kernel<<<1024, 256, 0, stream>>>(sim, simT, mask, ms1, ms2, posA, negA, nposA, pairA, ks);
  pairs_kernel<<<2048, 256, 0, stream>>>(posA, negA, nposA, lossB);
  final_kernel<<<1, 256, 0, stream>>>(lossB, pairA, out);
}

// Round 6
// 35.892 us; speedup vs baseline: 3.3618x; 1.1188x over previous
//
#include <hip/hip_runtime.h>

#define NN 512
#define DD 1024

typedef __attribute__((ext_vector_type(8))) short short8;
typedef __attribute__((ext_vector_type(4))) float f32x4;

__device__ __forceinline__ float fast_exp2(float x) {
#if __has_builtin(__builtin_amdgcn_exp2f)
  return __builtin_amdgcn_exp2f(x);
#else
  return __expf(x * 0.6931471805599453f);
#endif
}
__device__ __forceinline__ float fast_log2(float x) {
#if __has_builtin(__builtin_amdgcn_logf)
  return __builtin_amdgcn_logf(x);
#else
  return __logf(x) * 1.4426950408889634f;
#endif
}

// split f32 -> bf16 hi/lo (truncation; lo absorbs hi's error, net rel err ~2^-16)
__device__ __forceinline__ void cvt2(float f0, float f1, unsigned& hi, unsigned& lo) {
  const unsigned u0 = __float_as_uint(f0), u1 = __float_as_uint(f1);
  const unsigned h0 = u0 & 0xFFFF0000u, h1 = u1 & 0xFFFF0000u;
  const float r0 = f0 - __uint_as_float(h0);
  const float r1 = f1 - __uint_as_float(h1);
  hi = (u0 >> 16) | h1;
  lo = (__float_as_uint(r0) >> 16) | (__float_as_uint(r1) & 0xFFFF0000u);
}

__device__ __forceinline__ void store8(unsigned short* hp, unsigned short* lp,
                                       float4 f0, float4 f1) {
  uint4 hi, lo;
  cvt2(f0.x, f0.y, hi.x, lo.x);
  cvt2(f0.z, f0.w, hi.y, lo.y);
  cvt2(f1.x, f1.y, hi.z, lo.z);
  cvt2(f1.z, f1.w, hi.w, lo.w);
  *(uint4*)hp = hi;
  *(uint4*)lp = lo;
}

// ---------------- GEMM: sim partial = F1 * F2^T over a K-span, bf16-split MFMA ----------------
// 64x64 tile, 256 threads = 4 waves (2x2), each wave 32x32 via 2x2 16x16x32 frags.
// 3 MFMA products (hh, hl, lh) recover near-f32 precision. Writes sim AND simT partials.
// (verbatim from the round-3 version that PASSED; no prefetch)
__global__ __launch_bounds__(256) void gemm_kernel(const float* __restrict__ A,
                                                   const float* __restrict__ B,
                                                   float* __restrict__ simP,
                                                   float* __restrict__ simTP,
                                                   int ks) {
  __shared__ unsigned short Ah[64][40];  // row stride 80B (5x16B): aligned, ~2-way banks
  __shared__ unsigned short Al[64][40];
  __shared__ unsigned short Bh[64][40];
  __shared__ unsigned short Bl[64][40];
  const int t = threadIdx.x;
  const int lane = t & 63;
  const int w = t >> 6;
  const int wm = w >> 1, wn = w & 1;
  const int row0 = blockIdx.y * 64, col0 = blockIdx.x * 64;
  const int z = blockIdx.z;
  const int kspan = DD / ks;
  const int kbeg = z * kspan;
  const int srow = t >> 2;        // 0..63
  const int skq = (t & 3) << 3;   // 0,8,16,24

  f32x4 acc[2][2] = {{{0.f, 0.f, 0.f, 0.f}, {0.f, 0.f, 0.f, 0.f}},
                     {{0.f, 0.f, 0.f, 0.f}, {0.f, 0.f, 0.f, 0.f}}};

  const int ksel = (lane >> 4) << 3;   // 0,8,16,24 (k-offset of my frag slice)
  const int ar0 = wm * 32 + (lane & 15);
  const int br0 = wn * 32 + (lane & 15);

  for (int kb = 0; kb < kspan; kb += 32) {
    const float4 a0 = *(const float4*)&A[(row0 + srow) * DD + kbeg + kb + skq];
    const float4 a1 = *(const float4*)&A[(row0 + srow) * DD + kbeg + kb + skq + 4];
    const float4 b0 = *(const float4*)&B[(col0 + srow) * DD + kbeg + kb + skq];
    const float4 b1 = *(const float4*)&B[(col0 + srow) * DD + kbeg + kb + skq + 4];
    __syncthreads();
    store8(&Ah[srow][skq], &Al[srow][skq], a0, a1);
    store8(&Bh[srow][skq], &Bl[srow][skq], b0, b1);
    __syncthreads();
    short8 ah0 = *(const short8*)&Ah[ar0][ksel];
    short8 ah1 = *(const short8*)&Ah[ar0 + 16][ksel];
    short8 al0 = *(const short8*)&Al[ar0][ksel];
    short8 al1 = *(const short8*)&Al[ar0 + 16][ksel];
    short8 bh0 = *(const short8*)&Bh[br0][ksel];
    short8 bh1 = *(const short8*)&Bh[br0 + 16][ksel];
    short8 bl0 = *(const short8*)&Bl[br0][ksel];
    short8 bl1 = *(const short8*)&Bl[br0 + 16][ksel];
    acc[0][0] = __builtin_amdgcn_mfma_f32_16x16x32_bf16(ah0, bh0, acc[0][0], 0, 0, 0);
    acc[0][1] = __builtin_amdgcn_mfma_f32_16x16x32_bf16(ah0, bh1, acc[0][1], 0, 0, 0);
    acc[1][0] = __builtin_amdgcn_mfma_f32_16x16x32_bf16(ah1, bh0, acc[1][0], 0, 0, 0);
    acc[1][1] = __builtin_amdgcn_mfma_f32_16x16x32_bf16(ah1, bh1, acc[1][1], 0, 0, 0);
    acc[0][0] = __builtin_amdgcn_mfma_f32_16x16x32_bf16(ah0, bl0, acc[0][0], 0, 0, 0);
    acc[0][1] = __builtin_amdgcn_mfma_f32_16x16x32_bf16(ah0, bl1, acc[0][1], 0, 0, 0);
    acc[1][0] = __builtin_amdgcn_mfma_f32_16x16x32_bf16(ah1, bl0, acc[1][0], 0, 0, 0);
    acc[1][1] = __builtin_amdgcn_mfma_f32_16x16x32_bf16(ah1, bl1, acc[1][1], 0, 0, 0);
    acc[0][0] = __builtin_amdgcn_mfma_f32_16x16x32_bf16(al0, bh0, acc[0][0], 0, 0, 0);
    acc[0][1] = __builtin_amdgcn_mfma_f32_16x16x32_bf16(al0, bh1, acc[0][1], 0, 0, 0);
    acc[1][0] = __builtin_amdgcn_mfma_f32_16x16x32_bf16(al1, bh0, acc[1][0], 0, 0, 0);
    acc[1][1] = __builtin_amdgcn_mfma_f32_16x16x32_bf16(al1, bh1, acc[1][1], 0, 0, 0);
  }

  float* Cz = simP + (size_t)z * NN * NN;
  float* Tz = simTP + (size_t)z * NN * NN;
#pragma unroll
  for (int qm = 0; qm < 2; ++qm) {
    const int mb = row0 + wm * 32 + qm * 16 + ((lane >> 4) << 2);
#pragma unroll
    for (int qn = 0; qn < 2; ++qn) {
      const int n = col0 + wn * 32 + qn * 16 + (lane & 15);
#pragma unroll
      for (int r = 0; r < 4; ++r) Cz[(mb + r) * NN + n] = acc[qm][qn][r];
      *(f32x4*)&Tz[n * NN + mb] = acc[qm][qn];  // D-frag is m-contiguous: free transpose
    }
  }
}

// ---------------- Phase A: ballot-scan compaction into pos/neg lists (pre-scaled by log2e) ----------------
// (verbatim from the passed version)
__global__ __launch_bounds__(256) void prep_kernel(const float* __restrict__ simP,
                                                   const float* __restrict__ simTP,
                                                   const int* __restrict__ mask,
                                                   const unsigned char* __restrict__ ms1,
                                                   const unsigned char* __restrict__ ms2,
                                                   float* __restrict__ posA,
                                                   float* __restrict__ negA,
                                                   int* __restrict__ nposA,
                                                   float* __restrict__ pairA,
                                                   int ks) {
  __shared__ int wsum[4];
  const int b = blockIdx.x;         // 0..1023 (dir<<9 | idx)
  const int dir = b >> 9;
  const int idx = b & (NN - 1);
  const int t = threadIdx.x;
  const int lane = t & 63;
  const int w = t >> 6;
  const unsigned char sel = dir ? ms2[idx] : ms1[idx];
  if (!sel) {
    if (t == 0) { nposA[b] = -1; pairA[b] = 0.f; }
    return;
  }
  float v0 = 0.f, v1 = 0.f;
  int m0, m1;
  if (dir == 0) {
    for (int z = 0; z < ks; ++z) {
      v0 += simP[(size_t)z * NN * NN + idx * NN + t];
      v1 += simP[(size_t)z * NN * NN + idx * NN + t + 256];
    }
    m0 = mask[idx * NN + t];
    m1 = mask[idx * NN + t + 256];
  } else {
    for (int z = 0; z < ks; ++z) {
      v0 += simTP[(size_t)z * NN * NN + idx * NN + t];
      v1 += simTP[(size_t)z * NN * NN + idx * NN + t + 256];
    }
    m0 = mask[t * NN + idx];
    m1 = mask[(t + 256) * NN + idx];
  }
  const unsigned long long b0 = __ballot(m0 != 0);
  const unsigned long long b1 = __ballot(m1 != 0);
  const unsigned long long lt = (1ull << lane) - 1ull;
  const int c0 = __popcll(b0 & lt), c1 = __popcll(b1 & lt);
  const int t0 = __popcll(b0), t1 = __popcll(b1);
  if (lane == 0) wsum[w] = t0 + t1;
  __syncthreads();
  int wp = 0, npos = 0;
#pragma unroll
  for (int q = 0; q < 4; ++q) {
    const int s = wsum[q];
    npos += s;
    if (q < w) wp += s;
  }
  const float LOG2E = 1.4426950408889634f;
  float* pr = posA + (size_t)b * NN;
  float* ng = negA + (size_t)b * NN;
  // element order: wave-major, c0-block then c1-block within wave
  const int e0 = (w << 7) + lane;
  const int e1 = e0 + 64;
  const int pos0 = wp + c0;
  const int pos1 = wp + t0 + c1;
  if (m0) pr[pos0] = v0 * LOG2E; else ng[e0 - pos0] = v0 * LOG2E;
  if (m1) pr[pos1] = v1 * LOG2E; else ng[e1 - pos1] = v1 * LOG2E;
  if (t == 0) {
    nposA[b] = npos;
    pairA[b] = (float)npos * (float)(NN - npos);  // exact (<= 65536)
  }
}

// ---------------- Phase B: pair loss, fully balanced ----------------
// 2048 blocks: rd = bid>>1, h = bid&1 takes negatives [h*halfneg, ...).
// Each negative is handled by TWO adjacent threads (t and t^1), which split the
// positives by t&1 (both halves 16B-aligned). ~100% lane utilization,
// per-thread chains ~npos/2 evals, 4 accumulators (<= 2^64 product: safe, no segmenting).
__global__ __launch_bounds__(256) void pairs_kernel(const float* __restrict__ posA,
                                                    const float* __restrict__ negA,
                                                    const int* __restrict__ nposA,
                                                    float* __restrict__ lossB) {
  __shared__ __align__(16) float posL[NN];
  __shared__ float wred[4];
  const int bid = blockIdx.x;       // 0..2047
  const int rd = bid >> 1;
  const int h = bid & 1;
  const int t = threadIdx.x;
  const int lane = t & 63;
  const int w = t >> 6;
  const int npos = nposA[rd];
  if (npos < 0) {
    if (t == 0) lossB[bid] = 0.f;
    return;
  }
  for (int j = t; j < npos; j += 256) posL[j] = posA[(size_t)rd * NN + j];
  __syncthreads();
  const int nneg = NN - npos;
  const int halfneg = (nneg + 1) >> 1;
  const int nbeg = h * halfneg;
  const int nend = min(nneg, nbeg + halfneg);
  // this thread's positive half (both halves 16B-aligned: sp multiple of 4)
  const int sp = (npos >> 1) & ~3;
  const int ph = t & 1;
  const int pstart = ph ? sp : 0;
  const int pend = ph ? npos : sp;
  const float* pp = &posL[pstart];
  const int cnt = pend - pstart;
  const int cnt4 = cnt & ~3;

  float sum = 0.f;
  for (int n = nbeg + (t >> 1); n < nend; n += 128) {
    const float sn = negA[(size_t)rd * NN + n];   // log2e-scaled
    float l0 = 0.f, l1 = 0.f, l2 = 0.f, l3 = 0.f;
    float p0 = 1.f, p1 = 1.f, p2 = 1.f, p3 = 1.f;
#pragma unroll 2
    for (int k = 0; k < cnt4; k += 4) {
      const float4 sq = *(const float4*)&pp[k];   // 2 bases/wave: 2-way broadcast, free
      const float x0 = sn - sq.x; l0 += fmaxf(x0, 0.f); p0 = fmaf(p0, fast_exp2(-fabsf(x0)), p0);
      const float x1 = sn - sq.y; l1 += fmaxf(x1, 0.f); p1 = fmaf(p1, fast_exp2(-fabsf(x1)), p1);
      const float x2 = sn - sq.z; l2 += fmaxf(x2, 0.f); p2 = fmaf(p2, fast_exp2(-fabsf(x2)), p2);
      const float x3 = sn - sq.w; l3 += fmaxf(x3, 0.f); p3 = fmaf(p3, fast_exp2(-fabsf(x3)), p3);
    }
    for (int k = cnt4; k < cnt; ++k) {
      const float x = sn - pp[k];
      l0 += fmaxf(x, 0.f);
      p0 = fmaf(p0, fast_exp2(-fabsf(x)), p0);
    }
    sum += (((l0 + l1) + (l2 + l3)) +
            ((fast_log2(p0) + fast_log2(p1)) + (fast_log2(p2) + fast_log2(p3)))) *
           0.6931471805599453f;                   // back to natural units
  }
  for (int off = 32; off > 0; off >>= 1) sum += __shfl_down(sum, off);
  if (lane == 0) wred[w] = sum;
  __syncthreads();
  if (t == 0) lossB[bid] = (wred[0] + wred[1]) + (wred[2] + wred[3]);
}

// ---------------- Final: reduce partials, divide ----------------
__global__ __launch_bounds__(256) void final_kernel(const float* __restrict__ lossB,
                                                    const float* __restrict__ pairA,
                                                    float* __restrict__ out) {
  __shared__ double rl[256];
  __shared__ double rp[256];
  const int t = threadIdx.x;
  double al = 0.0, ap = 0.0;
  for (int i = t; i < 2048; i += 256) al += (double)lossB[i];
  for (int i = t; i < 1024; i += 256) ap += (double)pairA[i];
  rl[t] = al; rp[t] = ap; __syncthreads();
  for (int st = 128; st > 0; st >>= 1) {
    if (t < st) { rl[t] += rl[t + st]; rp[t] += rp[t + st]; }
    __syncthreads();
  }
  if (t == 0) {
    const double pn = rp[0];
    out[0] = (float)((pn > 0.0) ? rl[0] / pn : rl[0]);
  }
}

extern "C" void kernel_launch(void* const* d_in, const int* in_sizes, int n_in,
                              void* d_out, int out_size, void* d_ws, size_t ws_size,
                              hipStream_t stream) {
  const float* f1 = (const float*)d_in[0];
  const float* f2 = (const float*)d_in[1];
  const int* mask = (const int*)d_in[2];
  const unsigned char* ms1 = (const unsigned char*)d_in[3];
  const unsigned char* ms2 = (const unsigned char*)d_in[4];
  float* out = (float*)d_out;

  auto need = [](int ks) -> size_t {
    return ((size_t)2 * ks * NN * NN + 2u * 1024u * NN + 1024u + 1024u + 2048u) * sizeof(float);
  };
  const int ks = (ws_size >= need(4)) ? 4 : 1;   // ws observed ~268 MB; need(4) ~12.6 MB

  float* sim   = (float*)d_ws;                      // ks * 1 MB
  float* simT  = sim + (size_t)ks * NN * NN;        // ks * 1 MB
  float* posA  = simT + (size_t)ks * NN * NN;       // 2 MB
  float* negA  = posA + (size_t)1024 * NN;          // 2 MB
  int*   nposA = (int*)(negA + (size_t)1024 * NN);  // 4 KB
  float* pairA = (float*)(nposA + 1024);            // 4 KB
  float* lossB = pairA + 1024;                      // 8 KB

  gemm_kernel<<<dim3(8, 8, ks), 256, 0, stream>>>(f1, f2, sim, simT, ks);
  prep_kernel<<<1024, 256, 0, stream>>>(sim, simT, mask, ms1, ms2, posA, negA, nposA, pairA, ks);
  pairs_kernel<<<2048, 256, 0, stream>>>(posA, negA, nposA, lossB);
  final_kernel<<<1, 256, 0, stream>>>(lossB, pairA, out);
}

// Round 7
// 33.182 us; speedup vs baseline: 3.6364x; 1.0817x over previous
//
#include <hip/hip_runtime.h>

#define NN 512
#define DD 1024

typedef __attribute__((ext_vector_type(8))) short short8;
typedef __attribute__((ext_vector_type(4))) float f32x4;

__device__ __forceinline__ float fast_exp2(float x) {
#if __has_builtin(__builtin_amdgcn_exp2f)
  return __builtin_amdgcn_exp2f(x);
#else
  return __expf(x * 0.6931471805599453f);
#endif
}
__device__ __forceinline__ float fast_log2(float x) {
#if __has_builtin(__builtin_amdgcn_logf)
  return __builtin_amdgcn_logf(x);
#else
  return __logf(x) * 1.4426950408889634f;
#endif
}

// split f32 -> bf16 hi/lo (truncation; lo absorbs hi's error, net rel err ~2^-16)
__device__ __forceinline__ void cvt2(float f0, float f1, unsigned& hi, unsigned& lo) {
  const unsigned u0 = __float_as_uint(f0), u1 = __float_as_uint(f1);
  const unsigned h0 = u0 & 0xFFFF0000u, h1 = u1 & 0xFFFF0000u;
  const float r0 = f0 - __uint_as_float(h0);
  const float r1 = f1 - __uint_as_float(h1);
  hi = (u0 >> 16) | h1;
  lo = (__float_as_uint(r0) >> 16) | (__float_as_uint(r1) & 0xFFFF0000u);
}

__device__ __forceinline__ void store8(unsigned short* hp, unsigned short* lp,
                                       float4 f0, float4 f1) {
  uint4 hi, lo;
  cvt2(f0.x, f0.y, hi.x, lo.x);
  cvt2(f0.z, f0.w, hi.y, lo.y);
  cvt2(f1.x, f1.y, hi.z, lo.z);
  cvt2(f1.z, f1.w, hi.w, lo.w);
  *(uint4*)hp = hi;
  *(uint4*)lp = lo;
}

// ---------------- GEMM: sim partial = F1 * F2^T over a K-span, bf16-split MFMA ----------------
// 64x64 tile, 256 threads = 4 waves (2x2), each wave 32x32 via 2x2 16x16x32 frags.
// 3 MFMA products (hh, hl, lh) recover near-f32 precision. Writes sim AND simT partials.
// (verbatim structure from the passing round-3/6 version; only ks grows to 8 -> 2 blocks/CU)
__global__ __launch_bounds__(256) void gemm_kernel(const float* __restrict__ A,
                                                   const float* __restrict__ B,
                                                   float* __restrict__ simP,
                                                   float* __restrict__ simTP,
                                                   int ks) {
  __shared__ unsigned short Ah[64][40];  // row stride 80B (5x16B): aligned, ~2-way banks
  __shared__ unsigned short Al[64][40];
  __shared__ unsigned short Bh[64][40];
  __shared__ unsigned short Bl[64][40];
  const int t = threadIdx.x;
  const int lane = t & 63;
  const int w = t >> 6;
  const int wm = w >> 1, wn = w & 1;
  const int row0 = blockIdx.y * 64, col0 = blockIdx.x * 64;
  const int z = blockIdx.z;
  const int kspan = DD / ks;
  const int kbeg = z * kspan;
  const int srow = t >> 2;        // 0..63
  const int skq = (t & 3) << 3;   // 0,8,16,24

  f32x4 acc[2][2] = {{{0.f, 0.f, 0.f, 0.f}, {0.f, 0.f, 0.f, 0.f}},
                     {{0.f, 0.f, 0.f, 0.f}, {0.f, 0.f, 0.f, 0.f}}};

  const int ksel = (lane >> 4) << 3;   // 0,8,16,24 (k-offset of my frag slice)
  const int ar0 = wm * 32 + (lane & 15);
  const int br0 = wn * 32 + (lane & 15);

  for (int kb = 0; kb < kspan; kb += 32) {
    const float4 a0 = *(const float4*)&A[(row0 + srow) * DD + kbeg + kb + skq];
    const float4 a1 = *(const float4*)&A[(row0 + srow) * DD + kbeg + kb + skq + 4];
    const float4 b0 = *(const float4*)&B[(col0 + srow) * DD + kbeg + kb + skq];
    const float4 b1 = *(const float4*)&B[(col0 + srow) * DD + kbeg + kb + skq + 4];
    __syncthreads();
    store8(&Ah[srow][skq], &Al[srow][skq], a0, a1);
    store8(&Bh[srow][skq], &Bl[srow][skq], b0, b1);
    __syncthreads();
    short8 ah0 = *(const short8*)&Ah[ar0][ksel];
    short8 ah1 = *(const short8*)&Ah[ar0 + 16][ksel];
    short8 al0 = *(const short8*)&Al[ar0][ksel];
    short8 al1 = *(const short8*)&Al[ar0 + 16][ksel];
    short8 bh0 = *(const short8*)&Bh[br0][ksel];
    short8 bh1 = *(const short8*)&Bh[br0 + 16][ksel];
    short8 bl0 = *(const short8*)&Bl[br0][ksel];
    short8 bl1 = *(const short8*)&Bl[br0 + 16][ksel];
    acc[0][0] = __builtin_amdgcn_mfma_f32_16x16x32_bf16(ah0, bh0, acc[0][0], 0, 0, 0);
    acc[0][1] = __builtin_amdgcn_mfma_f32_16x16x32_bf16(ah0, bh1, acc[0][1], 0, 0, 0);
    acc[1][0] = __builtin_amdgcn_mfma_f32_16x16x32_bf16(ah1, bh0, acc[1][0], 0, 0, 0);
    acc[1][1] = __builtin_amdgcn_mfma_f32_16x16x32_bf16(ah1, bh1, acc[1][1], 0, 0, 0);
    acc[0][0] = __builtin_amdgcn_mfma_f32_16x16x32_bf16(ah0, bl0, acc[0][0], 0, 0, 0);
    acc[0][1] = __builtin_amdgcn_mfma_f32_16x16x32_bf16(ah0, bl1, acc[0][1], 0, 0, 0);
    acc[1][0] = __builtin_amdgcn_mfma_f32_16x16x32_bf16(ah1, bl0, acc[1][0], 0, 0, 0);
    acc[1][1] = __builtin_amdgcn_mfma_f32_16x16x32_bf16(ah1, bl1, acc[1][1], 0, 0, 0);
    acc[0][0] = __builtin_amdgcn_mfma_f32_16x16x32_bf16(al0, bh0, acc[0][0], 0, 0, 0);
    acc[0][1] = __builtin_amdgcn_mfma_f32_16x16x32_bf16(al0, bh1, acc[0][1], 0, 0, 0);
    acc[1][0] = __builtin_amdgcn_mfma_f32_16x16x32_bf16(al1, bh0, acc[1][0], 0, 0, 0);
    acc[1][1] = __builtin_amdgcn_mfma_f32_16x16x32_bf16(al1, bh1, acc[1][1], 0, 0, 0);
  }

  float* Cz = simP + (size_t)z * NN * NN;
  float* Tz = simTP + (size_t)z * NN * NN;
#pragma unroll
  for (int qm = 0; qm < 2; ++qm) {
    const int mb = row0 + wm * 32 + qm * 16 + ((lane >> 4) << 2);
#pragma unroll
    for (int qn = 0; qn < 2; ++qn) {
      const int n = col0 + wn * 32 + qn * 16 + (lane & 15);
#pragma unroll
      for (int r = 0; r < 4; ++r) Cz[(mb + r) * NN + n] = acc[qm][qn][r];
      *(f32x4*)&Tz[n * NN + mb] = acc[qm][qn];  // D-frag is m-contiguous: free transpose
    }
  }
}

// ---------------- Fused loss: compaction (LDS, verbatim prep logic) + balanced pair loop ----------------
// 2048 blocks: rd = bid>>1 picks (dir,row); h = bid&1 takes negatives [h*halfneg, ...).
// Both blocks of a pair redundantly compact (cheap, L2/L3-fed) -> no pos/neg global round-trip.
// Each negative handled by TWO adjacent threads splitting positives by t&1 (both halves
// 16B-aligned). Product-trick softplus: chains <= 2^64, one log2 per accumulator.
// NO cross-block protocol: partials go to global, final_kernel reads after kernel boundary.
__global__ __launch_bounds__(256) void loss_kernel(const float* __restrict__ simP,
                                                   const float* __restrict__ simTP,
                                                   const int* __restrict__ mask,
                                                   const unsigned char* __restrict__ ms1,
                                                   const unsigned char* __restrict__ ms2,
                                                   float* __restrict__ lossB,
                                                   float* __restrict__ pairB,
                                                   int ks) {
  __shared__ __align__(16) float posL[NN];
  __shared__ __align__(16) float negL[NN];
  __shared__ int wsum[4];
  __shared__ float wred[4];
  const int bid = blockIdx.x;       // 0..2047
  const int rd = bid >> 1;
  const int h = bid & 1;
  const int dir = rd >> 9;
  const int idx = rd & (NN - 1);
  const int t = threadIdx.x;
  const int lane = t & 63;
  const int w = t >> 6;
  const unsigned char sel = dir ? ms2[idx] : ms1[idx];   // block-uniform
  if (!sel) {
    if (t == 0) {
      lossB[bid] = 0.f;
      if (h == 0) pairB[rd] = 0.f;
    }
    return;
  }
  // ---- compaction (verbatim prep indexing, destination = LDS) ----
  float v0 = 0.f, v1 = 0.f;
  int m0, m1;
  if (dir == 0) {
    for (int zz = 0; zz < ks; ++zz) {
      v0 += simP[(size_t)zz * NN * NN + idx * NN + t];
      v1 += simP[(size_t)zz * NN * NN + idx * NN + t + 256];
    }
    m0 = mask[idx * NN + t];
    m1 = mask[idx * NN + t + 256];
  } else {
    for (int zz = 0; zz < ks; ++zz) {
      v0 += simTP[(size_t)zz * NN * NN + idx * NN + t];
      v1 += simTP[(size_t)zz * NN * NN + idx * NN + t + 256];
    }
    m0 = mask[t * NN + idx];
    m1 = mask[(t + 256) * NN + idx];
  }
  const unsigned long long b0 = __ballot(m0 != 0);
  const unsigned long long b1 = __ballot(m1 != 0);
  const unsigned long long lt = (1ull << lane) - 1ull;
  const int c0 = __popcll(b0 & lt), c1 = __popcll(b1 & lt);
  const int t0c = __popcll(b0), t1c = __popcll(b1);
  if (lane == 0) wsum[w] = t0c + t1c;
  __syncthreads();
  int wp = 0, npos = 0;
#pragma unroll
  for (int q = 0; q < 4; ++q) {
    const int s = wsum[q];
    npos += s;
    if (q < w) wp += s;
  }
  const float LOG2E = 1.4426950408889634f;
  const int e0 = (w << 7) + lane;
  const int e1 = e0 + 64;
  const int pos0 = wp + c0;
  const int pos1 = wp + t0c + c1;
  if (m0) posL[pos0] = v0 * LOG2E; else negL[e0 - pos0] = v0 * LOG2E;
  if (m1) posL[pos1] = v1 * LOG2E; else negL[e1 - pos1] = v1 * LOG2E;
  __syncthreads();

  // ---- balanced pair loop (verbatim round-6 logic; negatives now from LDS) ----
  const int nneg = NN - npos;
  const int halfneg = (nneg + 1) >> 1;
  const int nbeg = h * halfneg;
  const int nend = min(nneg, nbeg + halfneg);
  const int sp = (npos >> 1) & ~3;   // 16B-aligned split of positives
  const int ph = t & 1;
  const int pstart = ph ? sp : 0;
  const int pend = ph ? npos : sp;
  const float* pp = &posL[pstart];
  const int cnt = pend - pstart;
  const int cnt4 = cnt & ~3;

  float sum = 0.f;
  for (int n = nbeg + (t >> 1); n < nend; n += 128) {
    const float sn = negL[n];        // log2e-scaled; adjacent-lane broadcast
    float l0 = 0.f, l1 = 0.f, l2 = 0.f, l3 = 0.f;
    float p0 = 1.f, p1 = 1.f, p2 = 1.f, p3 = 1.f;
#pragma unroll 2
    for (int k = 0; k < cnt4; k += 4) {
      const float4 sq = *(const float4*)&pp[k];   // 2 bases/wave: 2-way broadcast, free
      const float x0 = sn - sq.x; l0 += fmaxf(x0, 0.f); p0 = fmaf(p0, fast_exp2(-fabsf(x0)), p0);
      const float x1 = sn - sq.y; l1 += fmaxf(x1, 0.f); p1 = fmaf(p1, fast_exp2(-fabsf(x1)), p1);
      const float x2 = sn - sq.z; l2 += fmaxf(x2, 0.f); p2 = fmaf(p2, fast_exp2(-fabsf(x2)), p2);
      const float x3 = sn - sq.w; l3 += fmaxf(x3, 0.f); p3 = fmaf(p3, fast_exp2(-fabsf(x3)), p3);
    }
    for (int k = cnt4; k < cnt; ++k) {
      const float x = sn - pp[k];
      l0 += fmaxf(x, 0.f);
      p0 = fmaf(p0, fast_exp2(-fabsf(x)), p0);
    }
    sum += (((l0 + l1) + (l2 + l3)) +
            ((fast_log2(p0) + fast_log2(p1)) + (fast_log2(p2) + fast_log2(p3)))) *
           0.6931471805599453f;                   // back to natural units
  }
  for (int off = 32; off > 0; off >>= 1) sum += __shfl_down(sum, off);
  if (lane == 0) wred[w] = sum;
  __syncthreads();
  if (t == 0) {
    lossB[bid] = (wred[0] + wred[1]) + (wred[2] + wred[3]);
    if (h == 0) pairB[rd] = (float)npos * (float)(NN - npos);  // exact (<= 65536)
  }
}

// ---------------- Final: reduce partials, divide ----------------
__global__ __launch_bounds__(256) void final_kernel(const float* __restrict__ lossB,
                                                    const float* __restrict__ pairB,
                                                    float* __restrict__ out) {
  __shared__ double rl[256];
  __shared__ double rp[256];
  const int t = threadIdx.x;
  double al = 0.0, ap = 0.0;
  for (int i = t; i < 2048; i += 256) al += (double)lossB[i];
  for (int i = t; i < 1024; i += 256) ap += (double)pairB[i];
  rl[t] = al; rp[t] = ap; __syncthreads();
  for (int st = 128; st > 0; st >>= 1) {
    if (t < st) { rl[t] += rl[t + st]; rp[t] += rp[t + st]; }
    __syncthreads();
  }
  if (t == 0) {
    const double pn = rp[0];
    out[0] = (float)((pn > 0.0) ? rl[0] / pn : rl[0]);
  }
}

extern "C" void kernel_launch(void* const* d_in, const int* in_sizes, int n_in,
                              void* d_out, int out_size, void* d_ws, size_t ws_size,
                              hipStream_t stream) {
  const float* f1 = (const float*)d_in[0];
  const float* f2 = (const float*)d_in[1];
  const int* mask = (const int*)d_in[2];
  const unsigned char* ms1 = (const unsigned char*)d_in[3];
  const unsigned char* ms2 = (const unsigned char*)d_in[4];
  float* out = (float*)d_out;

  auto need = [](int ks) -> size_t {
    return ((size_t)2 * ks * NN * NN + 2048u + 1024u) * sizeof(float);
  };
  const int ks = (ws_size >= need(8)) ? 8 : ((ws_size >= need(4)) ? 4 : 1);

  float* sim   = (float*)d_ws;                      // ks * 1 MB
  float* simT  = sim + (size_t)ks * NN * NN;        // ks * 1 MB
  float* lossB = simT + (size_t)ks * NN * NN;       // 8 KB
  float* pairB = lossB + 2048;                      // 4 KB

  gemm_kernel<<<dim3(8, 8, ks), 256, 0, stream>>>(f1, f2, sim, simT, ks);
  loss_kernel<<<2048, 256, 0, stream>>>(sim, simT, mask, ms1, ms2, lossB, pairB, ks);
  final_kernel<<<1, 256, 0, stream>>>(lossB, pairB, out);
}

// Round 8
// 28.142 us; speedup vs baseline: 4.2877x; 1.1791x over previous
//
#include <hip/hip_runtime.h>

#define NN 512
#define DD 1024

typedef __attribute__((ext_vector_type(8))) short short8;
typedef __attribute__((ext_vector_type(4))) float f32x4;

__device__ __forceinline__ float fast_exp2(float x) {
#if __has_builtin(__builtin_amdgcn_exp2f)
  return __builtin_amdgcn_exp2f(x);
#else
  return __expf(x * 0.6931471805599453f);
#endif
}
__device__ __forceinline__ float fast_log2(float x) {
#if __has_builtin(__builtin_amdgcn_logf)
  return __builtin_amdgcn_logf(x);
#else
  return __logf(x) * 1.4426950408889634f;
#endif
}

// split f32 -> bf16 hi/lo (truncation; lo absorbs hi's error, net rel err ~2^-16)
__device__ __forceinline__ void cvt2(float f0, float f1, unsigned& hi, unsigned& lo) {
  const unsigned u0 = __float_as_uint(f0), u1 = __float_as_uint(f1);
  const unsigned h0 = u0 & 0xFFFF0000u, h1 = u1 & 0xFFFF0000u;
  const float r0 = f0 - __uint_as_float(h0);
  const float r1 = f1 - __uint_as_float(h1);
  hi = (u0 >> 16) | h1;
  lo = (__float_as_uint(r0) >> 16) | (__float_as_uint(r1) & 0xFFFF0000u);
}

__device__ __forceinline__ void store8(unsigned short* hp, unsigned short* lp,
                                       float4 f0, float4 f1) {
  uint4 hi, lo;
  cvt2(f0.x, f0.y, hi.x, lo.x);
  cvt2(f0.z, f0.w, hi.y, lo.y);
  cvt2(f1.x, f1.y, hi.z, lo.z);
  cvt2(f1.z, f1.w, hi.w, lo.w);
  *(uint4*)hp = hi;
  *(uint4*)lp = lo;
}

// ---------------- GEMM: sim partial = F1 * F2^T over a K-span, bf16-split MFMA ----------------
// (verbatim from the passing round-6/7 version)
__global__ __launch_bounds__(256) void gemm_kernel(const float* __restrict__ A,
                                                   const float* __restrict__ B,
                                                   float* __restrict__ simP,
                                                   float* __restrict__ simTP,
                                                   int ks) {
  __shared__ unsigned short Ah[64][40];  // row stride 80B (5x16B): aligned, ~2-way banks
  __shared__ unsigned short Al[64][40];
  __shared__ unsigned short Bh[64][40];
  __shared__ unsigned short Bl[64][40];
  const int t = threadIdx.x;
  const int lane = t & 63;
  const int w = t >> 6;
  const int wm = w >> 1, wn = w & 1;
  const int row0 = blockIdx.y * 64, col0 = blockIdx.x * 64;
  const int z = blockIdx.z;
  const int kspan = DD / ks;
  const int kbeg = z * kspan;
  const int srow = t >> 2;        // 0..63
  const int skq = (t & 3) << 3;   // 0,8,16,24

  f32x4 acc[2][2] = {{{0.f, 0.f, 0.f, 0.f}, {0.f, 0.f, 0.f, 0.f}},
                     {{0.f, 0.f, 0.f, 0.f}, {0.f, 0.f, 0.f, 0.f}}};

  const int ksel = (lane >> 4) << 3;   // 0,8,16,24 (k-offset of my frag slice)
  const int ar0 = wm * 32 + (lane & 15);
  const int br0 = wn * 32 + (lane & 15);

  for (int kb = 0; kb < kspan; kb += 32) {
    const float4 a0 = *(const float4*)&A[(row0 + srow) * DD + kbeg + kb + skq];
    const float4 a1 = *(const float4*)&A[(row0 + srow) * DD + kbeg + kb + skq + 4];
    const float4 b0 = *(const float4*)&B[(col0 + srow) * DD + kbeg + kb + skq];
    const float4 b1 = *(const float4*)&B[(col0 + srow) * DD + kbeg + kb + skq + 4];
    __syncthreads();
    store8(&Ah[srow][skq], &Al[srow][skq], a0, a1);
    store8(&Bh[srow][skq], &Bl[srow][skq], b0, b1);
    __syncthreads();
    short8 ah0 = *(const short8*)&Ah[ar0][ksel];
    short8 ah1 = *(const short8*)&Ah[ar0 + 16][ksel];
    short8 al0 = *(const short8*)&Al[ar0][ksel];
    short8 al1 = *(const short8*)&Al[ar0 + 16][ksel];
    short8 bh0 = *(const short8*)&Bh[br0][ksel];
    short8 bh1 = *(const short8*)&Bh[br0 + 16][ksel];
    short8 bl0 = *(const short8*)&Bl[br0][ksel];
    short8 bl1 = *(const short8*)&Bl[br0 + 16][ksel];
    acc[0][0] = __builtin_amdgcn_mfma_f32_16x16x32_bf16(ah0, bh0, acc[0][0], 0, 0, 0);
    acc[0][1] = __builtin_amdgcn_mfma_f32_16x16x32_bf16(ah0, bh1, acc[0][1], 0, 0, 0);
    acc[1][0] = __builtin_amdgcn_mfma_f32_16x16x32_bf16(ah1, bh0, acc[1][0], 0, 0, 0);
    acc[1][1] = __builtin_amdgcn_mfma_f32_16x16x32_bf16(ah1, bh1, acc[1][1], 0, 0, 0);
    acc[0][0] = __builtin_amdgcn_mfma_f32_16x16x32_bf16(ah0, bl0, acc[0][0], 0, 0, 0);
    acc[0][1] = __builtin_amdgcn_mfma_f32_16x16x32_bf16(ah0, bl1, acc[0][1], 0, 0, 0);
    acc[1][0] = __builtin_amdgcn_mfma_f32_16x16x32_bf16(ah1, bl0, acc[1][0], 0, 0, 0);
    acc[1][1] = __builtin_amdgcn_mfma_f32_16x16x32_bf16(ah1, bl1, acc[1][1], 0, 0, 0);
    acc[0][0] = __builtin_amdgcn_mfma_f32_16x16x32_bf16(al0, bh0, acc[0][0], 0, 0, 0);
    acc[0][1] = __builtin_amdgcn_mfma_f32_16x16x32_bf16(al0, bh1, acc[0][1], 0, 0, 0);
    acc[1][0] = __builtin_amdgcn_mfma_f32_16x16x32_bf16(al1, bh0, acc[1][0], 0, 0, 0);
    acc[1][1] = __builtin_amdgcn_mfma_f32_16x16x32_bf16(al1, bh1, acc[1][1], 0, 0, 0);
  }

  float* Cz = simP + (size_t)z * NN * NN;
  float* Tz = simTP + (size_t)z * NN * NN;
#pragma unroll
  for (int qm = 0; qm < 2; ++qm) {
    const int mb = row0 + wm * 32 + qm * 16 + ((lane >> 4) << 2);
#pragma unroll
    for (int qn = 0; qn < 2; ++qn) {
      const int n = col0 + wn * 32 + qn * 16 + (lane & 15);
#pragma unroll
      for (int r = 0; r < 4; ++r) Cz[(mb + r) * NN + n] = acc[qm][qn][r];
      *(f32x4*)&Tz[n * NN + mb] = acc[qm][qn];  // D-frag is m-contiguous: free transpose
    }
  }
}

// ---------------- Fused loss: 512 threads per (dir,row); single compaction; balanced pairs ----------------
// One block per rd: thread t owns element t (1-elem ballot-scan). Pair loop: thread pair
// (2n, 2n+1) handles negative n, splitting positives by t&1 at 16B-aligned midpoint —
// identical (p,n) coverage to the passing round-6/7 mapping. KS templated: partial loads unroll.
template <int KS>
__global__ __launch_bounds__(512) void loss_kernel(const float* __restrict__ simP,
                                                   const float* __restrict__ simTP,
                                                   const int* __restrict__ mask,
                                                   const unsigned char* __restrict__ ms1,
                                                   const unsigned char* __restrict__ ms2,
                                                   float* __restrict__ lossB,
                                                   float* __restrict__ pairB) {
  __shared__ __align__(16) float posL[NN];
  __shared__ __align__(16) float negL[NN];
  __shared__ int wsum[8];
  __shared__ float wred[8];
  const int rd = blockIdx.x;        // 0..1023 (dir<<9 | idx)
  const int dir = rd >> 9;
  const int idx = rd & (NN - 1);
  const int t = threadIdx.x;        // 0..511
  const int lane = t & 63;
  const int w = t >> 6;             // 0..7
  const unsigned char sel = dir ? ms2[idx] : ms1[idx];   // block-uniform
  if (!sel) {
    if (t == 0) { lossB[rd] = 0.f; pairB[rd] = 0.f; }
    return;
  }
  // ---- compaction: thread t owns element t ----
  float v = 0.f;
  int m;
  if (dir == 0) {
#pragma unroll
    for (int zz = 0; zz < KS; ++zz) v += simP[(size_t)zz * NN * NN + idx * NN + t];
    m = mask[idx * NN + t];
  } else {
#pragma unroll
    for (int zz = 0; zz < KS; ++zz) v += simTP[(size_t)zz * NN * NN + idx * NN + t];
    m = mask[t * NN + idx];
  }
  const unsigned long long bal = __ballot(m != 0);
  const unsigned long long lt = (1ull << lane) - 1ull;
  const int c = __popcll(bal & lt);
  const int tc = __popcll(bal);
  if (lane == 0) wsum[w] = tc;
  __syncthreads();
  int wp = 0, npos = 0;
#pragma unroll
  for (int q = 0; q < 8; ++q) {
    const int s = wsum[q];
    npos += s;
    if (q < w) wp += s;
  }
  const float LOG2E = 1.4426950408889634f;
  const int pos = wp + c;           // positives among elements 0..t-1 (within my class)
  if (m) posL[pos] = v * LOG2E;
  else   negL[t - pos] = v * LOG2E;
  __syncthreads();

  // ---- balanced pair loop (same mapping as passing rounds 6/7) ----
  const int nneg = NN - npos;
  const int sp = (npos >> 1) & ~3;  // 16B-aligned split of positives
  const int ph = t & 1;
  const float* pp = &posL[ph ? sp : 0];
  const int cnt = (ph ? npos : sp) - (ph ? sp : 0);
  const int cnt4 = cnt & ~3;

  float sum = 0.f;                  // log2-domain; convert once at the end
  for (int n = (t >> 1); n < nneg; n += 256) {
    const float yn = negL[n];       // adjacent-lane broadcast
    float l0 = 0.f, l1 = 0.f, l2 = 0.f, l3 = 0.f;
    float p0 = 1.f, p1 = 1.f, p2 = 1.f, p3 = 1.f;
#pragma unroll 2
    for (int k = 0; k < cnt4; k += 4) {
      const float4 sq = *(const float4*)&pp[k];   // 2 bases/wave: 2-way broadcast, free
      const float x0 = yn - sq.x; l0 += fmaxf(x0, 0.f); p0 = fmaf(p0, fast_exp2(-fabsf(x0)), p0);
      const float x1 = yn - sq.y; l1 += fmaxf(x1, 0.f); p1 = fmaf(p1, fast_exp2(-fabsf(x1)), p1);
      const float x2 = yn - sq.z; l2 += fmaxf(x2, 0.f); p2 = fmaf(p2, fast_exp2(-fabsf(x2)), p2);
      const float x3 = yn - sq.w; l3 += fmaxf(x3, 0.f); p3 = fmaf(p3, fast_exp2(-fabsf(x3)), p3);
    }
    for (int k = cnt4; k < cnt; ++k) {
      const float x = yn - pp[k];
      l0 += fmaxf(x, 0.f);
      p0 = fmaf(p0, fast_exp2(-fabsf(x)), p0);
    }
    sum += ((l0 + l1) + (l2 + l3)) +
           ((fast_log2(p0) + fast_log2(p1)) + (fast_log2(p2) + fast_log2(p3)));
  }
  sum *= 0.6931471805599453f;       // back to natural units, once

  for (int off = 32; off > 0; off >>= 1) sum += __shfl_down(sum, off);
  if (lane == 0) wred[w] = sum;
  __syncthreads();
  if (t == 0) {
    float bs = 0.f;
#pragma unroll
    for (int q = 0; q < 8; ++q) bs += wred[q];
    lossB[rd] = bs;
    pairB[rd] = (float)npos * (float)(NN - npos);  // exact (<= 65536)
  }
}

// ---------------- Final: reduce partials, divide ----------------
__global__ __launch_bounds__(256) void final_kernel(const float* __restrict__ lossB,
                                                    const float* __restrict__ pairB,
                                                    float* __restrict__ out) {
  __shared__ double rl[256];
  __shared__ double rp[256];
  const int t = threadIdx.x;
  double al = 0.0, ap = 0.0;
  for (int i = t; i < 1024; i += 256) { al += (double)lossB[i]; ap += (double)pairB[i]; }
  rl[t] = al; rp[t] = ap; __syncthreads();
  for (int st = 128; st > 0; st >>= 1) {
    if (t < st) { rl[t] += rl[t + st]; rp[t] += rp[t + st]; }
    __syncthreads();
  }
  if (t == 0) {
    const double pn = rp[0];
    out[0] = (float)((pn > 0.0) ? rl[0] / pn : rl[0]);
  }
}

extern "C" void kernel_launch(void* const* d_in, const int* in_sizes, int n_in,
                              void* d_out, int out_size, void* d_ws, size_t ws_size,
                              hipStream_t stream) {
  const float* f1 = (const float*)d_in[0];
  const float* f2 = (const float*)d_in[1];
  const int* mask = (const int*)d_in[2];
  const unsigned char* ms1 = (const unsigned char*)d_in[3];
  const unsigned char* ms2 = (const unsigned char*)d_in[4];
  float* out = (float*)d_out;

  auto need = [](int ks) -> size_t {
    return ((size_t)2 * ks * NN * NN + 1024u + 1024u) * sizeof(float);
  };
  const int ks = (ws_size >= need(8)) ? 8 : ((ws_size >= need(4)) ? 4 : 1);

  float* sim   = (float*)d_ws;                      // ks * 1 MB
  float* simT  = sim + (size_t)ks * NN * NN;        // ks * 1 MB
  float* lossB = simT + (size_t)ks * NN * NN;       // 4 KB
  float* pairB = lossB + 1024;                      // 4 KB

  gemm_kernel<<<dim3(8, 8, ks), 256, 0, stream>>>(f1, f2, sim, simT, ks);
  if (ks == 8) {
    loss_kernel<8><<<1024, 512, 0, stream>>>(sim, simT, mask, ms1, ms2, lossB, pairB);
  } else if (ks == 4) {
    loss_kernel<4><<<1024, 512, 0, stream>>>(sim, simT, mask, ms1, ms2, lossB, pairB);
  } else {
    loss_kernel<1><<<1024, 512, 0, stream>>>(sim, simT, mask, ms1, ms2, lossB, pairB);
  }
  final_kernel<<<1, 256, 0, stream>>>(lossB, pairB, out);
}